// Round 1
// baseline (274.889 us; speedup 1.0000x reference)
//
#include <hip/hip_runtime.h>
#include <math.h>

#define NN 50000
#define E0 640000
#define ET 690000   // E0 + NN self loops
#define F1 128
#define D1 256      // 8 heads * 32
#define C2 16
#define NB 196      // ceil(NN/256)
#define MPAD 50048  // 391*128, padded node count for MFMA tiles
#define PADK 136    // 128 + 8 pad (breaks ds_read_b128 bank conflicts)
#define LOG2E 1.4426950408889634f
#define NBK1 782    // ceil(NN/64) node-blocks for agg1

typedef _Float16 f16x8 __attribute__((ext_vector_type(8)));
typedef _Float16 h2 __attribute__((ext_vector_type(2)));
typedef __attribute__((ext_vector_type(4))) float f32x4;

__device__ __forceinline__ unsigned short f2h(float f) {
  union { _Float16 h; unsigned short u; } c;
  c.h = (_Float16)f;
  return c.u;
}
__device__ __forceinline__ float h2f(unsigned short u) {
  union { unsigned short u; _Float16 h; } c; c.u = u; return (float)c.h;
}
__device__ __forceinline__ h2 u2h2(unsigned u) {
  union { unsigned u; h2 h; } c; c.u = u; return c.h;
}
__device__ __forceinline__ unsigned h22u(h2 h) {
  union { h2 h; unsigned u; } c; c.h = h; return c.u;
}

// DPP-based lane-group sums: v_add_f32 with DPP modifier, no DS ops.
// 0xB1 = quad_perm [1,0,3,2] (xor 1), 0x4E = quad_perm [2,3,0,1] (xor 2),
// 0x124 = row_ror:4, 0x128 = row_ror:8 (within 16-lane row).
template <int CTRL>
__device__ __forceinline__ float dpp_add(float c) {
  int t = __builtin_amdgcn_update_dpp(0, __builtin_bit_cast(int, c), CTRL, 0xF, 0xF, true);
  return c + __builtin_bit_cast(float, t);
}

// ---------------- prep: weight converts + degree histogram ----------------
// blocks [0,256): wt | [256,288): wt2 | rest: edge histogram.
__global__ __launch_bounds__(256) void k_prep(
    const float* __restrict__ Wl, const float* __restrict__ Wr,
    const float* __restrict__ W2l, const float* __restrict__ W2r,
    const int* __restrict__ ei,
    unsigned short* __restrict__ wt, unsigned short* __restrict__ wt2,
    int* __restrict__ deg) {
  const int b = blockIdx.x;
  if (b < 256) {
    int tid = b * 256 + threadIdx.x;            // = n*128 + k
    int n = tid >> 7, k = tid & 127;
    float v = (n < 256) ? Wl[k * 256 + n] : Wr[k * 256 + (n - 256)];
    wt[tid] = f2h(v);
  } else if (b < 288) {
    int tid = (b - 256) * 256 + threadIdx.x;    // = n*256 + k
    int n = tid >> 8, k = tid & 255;
    float v = (n < 16) ? W2l[k * 16 + n] : W2r[k * 16 + (n - 16)];
    wt2[tid] = f2h(v);
  } else {
    int e = (b - 288) * 256 + threadIdx.x;
    if (e >= ET) return;
    int d = (e < E0) ? ei[E0 + e] : (e - E0);
    atomicAdd(&deg[d], 1);
  }
}

// ---------------- Layer-1 GEMM via MFMA (fp16) ----------------
// C[M=50048, N=512] = x(f32, converted in staging) @ Wt^T.
// Outputs HEAD-MAJOR: out[head][node][32].
__global__ __launch_bounds__(256) void k_gemm1m(
    const float* __restrict__ x, const unsigned short* __restrict__ wt,
    unsigned short* __restrict__ xlh, unsigned short* __restrict__ xrh) {
  __shared__ unsigned short Al[128 * PADK];
  __shared__ unsigned short Bl[128 * PADK];
  const int t = threadIdx.x;
  const int m0 = blockIdx.x * 128;
  const int n0 = blockIdx.y * 128;
  {
    const int r = t >> 4;             // 0..15
    const int c = (t & 15) * 8;
#pragma unroll
    for (int p = 0; p < 8; ++p) {
      const int row = r + p * 16;
      const int rg = m0 + row;
      const float* xp = &x[(size_t)(rg < NN ? rg : NN - 1) * F1 + c];
      float4 lo = *(const float4*)xp;
      float4 hi = *(const float4*)(xp + 4);
      h2 q0 = h2{(_Float16)lo.x, (_Float16)lo.y};
      h2 q1 = h2{(_Float16)lo.z, (_Float16)lo.w};
      h2 q2 = h2{(_Float16)hi.x, (_Float16)hi.y};
      h2 q3 = h2{(_Float16)hi.z, (_Float16)hi.w};
      uint4 st; st.x = h22u(q0); st.y = h22u(q1); st.z = h22u(q2); st.w = h22u(q3);
      *(uint4*)&Al[row * PADK + c] = st;
      *(float4*)&Bl[row * PADK + c] = *(const float4*)&wt[(size_t)(n0 + row) * F1 + c];
    }
  }
  __syncthreads();
  const int wave = t >> 6, lane = t & 63;
  const int mw = (wave >> 1) * 64, nw = (wave & 1) * 64;
  const int fr = lane & 15, fq = lane >> 4;
  f32x4 acc[4][4] = {};
#pragma unroll
  for (int ks = 0; ks < 4; ++ks) {
    const int ko = ks * 32 + fq * 8;
    f16x8 a[4], b[4];
#pragma unroll
    for (int i = 0; i < 4; ++i)
      a[i] = *(const f16x8*)&Al[(mw + i * 16 + fr) * PADK + ko];
#pragma unroll
    for (int j = 0; j < 4; ++j)
      b[j] = *(const f16x8*)&Bl[(nw + j * 16 + fr) * PADK + ko];
#pragma unroll
    for (int i = 0; i < 4; ++i)
#pragma unroll
      for (int j = 0; j < 4; ++j)
        acc[i][j] = __builtin_amdgcn_mfma_f32_16x16x32_f16(a[i], b[j], acc[i][j], 0, 0, 0);
  }
  unsigned short* outp = (n0 < 256) ? xlh : xrh;
  const int cb = (n0 & 255) + nw + fr;
#pragma unroll
  for (int j = 0; j < 4; ++j) {
    const int col = cb + j * 16;
    const int head = col >> 5, f = col & 31;
    unsigned short* hp = outp + (size_t)head * NN * 32 + f;
#pragma unroll
    for (int i = 0; i < 4; ++i) {
      const int gm0 = m0 + mw + i * 16 + fq * 4;
#pragma unroll
      for (int r = 0; r < 4; ++r) {
        const int gm = gm0 + r;
        if (gm < NN) hp[(size_t)gm * 32] = f2h(acc[i][j][r]);
      }
    }
  }
}

// ---------------- CSR scan/scatter ----------------
__global__ __launch_bounds__(256) void k_scan_part(const int* __restrict__ deg,
                                                   int* __restrict__ part) {
  int i = blockIdx.x * 256 + threadIdx.x;
  int v = (i < NN) ? deg[i] : 0;
  v += __shfl_xor(v, 1);  v += __shfl_xor(v, 2);  v += __shfl_xor(v, 4);
  v += __shfl_xor(v, 8);  v += __shfl_xor(v, 16); v += __shfl_xor(v, 32);
  __shared__ int w[4];
  if ((threadIdx.x & 63) == 0) w[threadIdx.x >> 6] = v;
  __syncthreads();
  if (threadIdx.x == 0) part[blockIdx.x] = w[0] + w[1] + w[2] + w[3];
}

// Block-local scan + inline prefix over part[0..b).
// Also histograms degree buckets (64 buckets, REVERSED so high degree = low
// bucket -> high-degree waves launch first in agg1).
__global__ __launch_bounds__(256) void k_scan_apply(int* __restrict__ deg,
                                                    const int* __restrict__ part,
                                                    int* __restrict__ offs,
                                                    int* __restrict__ bhist) {
  __shared__ int lds[256];
  __shared__ int red[4];
  __shared__ int bh[64];
  const int b = blockIdx.x, t = threadIdx.x;
  const int i = b * 256 + t;
  int v = (i < NN) ? deg[i] : 0;
  lds[t] = v;
  if (t < 64) bh[t] = 0;
  // prefix of preceding blocks' partial sums
  int pp = 0;
  for (int j = t; j < b; j += 256) pp += part[j];
  pp += __shfl_xor(pp, 1);  pp += __shfl_xor(pp, 2);  pp += __shfl_xor(pp, 4);
  pp += __shfl_xor(pp, 8);  pp += __shfl_xor(pp, 16); pp += __shfl_xor(pp, 32);
  if ((t & 63) == 0) red[t >> 6] = pp;
  __syncthreads();
  if (i < NN) {
    int bkt = 63 - (v < 63 ? v : 63);
    atomicAdd(&bh[bkt], 1);
  }
  const int prefix = red[0] + red[1] + red[2] + red[3];
  for (int off = 1; off < 256; off <<= 1) {
    int u = (t >= off) ? lds[t - off] : 0;
    __syncthreads();
    lds[t] += u;
    __syncthreads();
  }
  int excl = prefix + lds[t] - v;
  if (i < NN) { offs[i] = excl; deg[i] = excl; }  // deg becomes cursor
  if (b == NB - 1 && t == 255) offs[NN] = prefix + lds[255];
  if (t < 64 && bh[t] > 0) atomicAdd(&bhist[t], bh[t]);
}

// Edge scatter; wave 0 of block 0 additionally scans the 64 degree buckets
// into bcur (exclusive prefix), consumed by k_perm.
__global__ void k_scatter(const int* __restrict__ ei, int* __restrict__ cur,
                          unsigned short* __restrict__ csr,
                          const int* __restrict__ bhist, int* __restrict__ bcur) {
  if (blockIdx.x == 0 && threadIdx.x < 64) {
    int t = threadIdx.x;
    int v = bhist[t];
    int s = v;
    for (int off = 1; off < 64; off <<= 1) {
      int u = __shfl_up(s, off);
      if (t >= off) s += u;
    }
    bcur[t] = s - v;  // exclusive scan
  }
  int e = blockIdx.x * 256 + threadIdx.x;
  if (e >= ET) return;
  int s, d;
  if (e < E0) { s = ei[e]; d = ei[E0 + e]; } else { s = d = e - E0; }
  int pos = atomicAdd(&cur[d], 1);
  csr[pos] = (unsigned short)s;   // node ids < 65536
}

// Degree-sorted node permutation (counting sort, 64 buckets).
// LDS two-phase to keep global atomics at 64/block.
__global__ __launch_bounds__(256) void k_perm(const int* __restrict__ offs,
                                              int* __restrict__ bcur,
                                              int* __restrict__ perm) {
  __shared__ int lh[64];
  __shared__ int lbase[64];
  const int t = threadIdx.x;
  const int i = blockIdx.x * 256 + t;
  if (t < 64) lh[t] = 0;
  __syncthreads();
  int bkt = 0, lpos = 0;
  const bool valid = i < NN;
  if (valid) {
    int d = offs[i + 1] - offs[i];
    bkt = 63 - (d < 63 ? d : 63);
    lpos = atomicAdd(&lh[bkt], 1);
  }
  __syncthreads();
  if (t < 64 && lh[t] > 0) lbase[t] = atomicAdd(&bcur[t], lh[t]);
  __syncthreads();
  if (valid) perm[lbase[bkt] + lpos] = i;
}

// ---------------- Layer-1 aggregation (head-pinned, 16 nodes/wave) ----------------
// head = blockIdx&7 pins each head's 3.2 MB slice to one XCD L2 (validated
// R9/R10: FETCH 165->56 MB). One wave = 16 nodes x 1 head; each 4-lane group
// owns one node's edge loop; p group-uniform -> no epilogue reduction.
// Nodes visited in degree-sorted order (perm) so the 16 groups of a wave have
// near-equal trip counts -> kills the E[max of 16] divergence tax (~1.6x).
__global__ __launch_bounds__(256) void k_agg1(
    const unsigned short* __restrict__ xlh, const unsigned short* __restrict__ xrh,
    unsigned short* __restrict__ hb,
    const int* __restrict__ offs, const unsigned short* __restrict__ csr,
    const float* __restrict__ att, const float* __restrict__ b1,
    const int* __restrict__ perm) {
  const int b = blockIdx.x;
  const int head = b & 7;
  const int wave = threadIdx.x >> 6;
  const int lane = threadIdx.x & 63;
  const int g = lane >> 2;          // node group 0..15
  const int j4 = lane & 3;          // lane within group
  const int idxn = (b >> 3) * 64 + wave * 16 + g;
  const bool valid = idxn < NN;
  const int n = valid ? perm[idxn] : 0;
  const int colh = j4 * 8;          // feat offset within head
  const int col = head * 32 + colh; // global feat col (att/b1)
  const unsigned short* xlhead = xlh + (size_t)head * NN * 32;

  const uint4 xru = *(const uint4*)&xrh[((size_t)head * NN + n) * 32 + colh];
  h2 xr2[4];
  xr2[0] = u2h2(xru.x); xr2[1] = u2h2(xru.y);
  xr2[2] = u2h2(xru.z); xr2[3] = u2h2(xru.w);
  float at8[8];
  *(float4*)&at8[0] = *(const float4*)&att[col];
  *(float4*)&at8[4] = *(const float4*)&att[col + 4];
  h2 ath6[4], ath4[4];
#pragma unroll
  for (int j = 0; j < 4; ++j) {
    ath6[j] = h2{(_Float16)(at8[2 * j] * (0.6f * LOG2E)),
                 (_Float16)(at8[2 * j + 1] * (0.6f * LOG2E))};
    ath4[j] = h2{(_Float16)(at8[2 * j] * (0.4f * LOG2E)),
                 (_Float16)(at8[2 * j + 1] * (0.4f * LOG2E))};
  }
  float l = 0.f;
  h2 acc2[4] = {h2{0, 0}, h2{0, 0}, h2{0, 0}, h2{0, 0}};
  const int beg = valid ? offs[n] : 0;
  const int fin = valid ? offs[n + 1] : 0;

  auto score = [&](const h2* xh) -> float {
    float cv = 0.f, ca = 0.f;
#pragma unroll
    for (int j = 0; j < 4; ++j) {
      h2 v = xh[j] + xr2[j];
      h2 a = u2h2(h22u(v) & 0x7FFF7FFFu);       // |v| per half
      cv = __builtin_amdgcn_fdot2(v, ath6[j], cv, false);
      ca = __builtin_amdgcn_fdot2(a, ath4[j], ca, false);
    }
    float c = cv + ca;
    c = dpp_add<0xB1>(c);             // + lane^1 (quad_perm, no DS op)
    c = dpp_add<0x4E>(c);             // + lane^2 -> group total in all 4 lanes
    return c;
  };

  int idx = beg;
  for (; idx + 1 < fin; idx += 2) {
    const int s0 = csr[idx], s1 = csr[idx + 1];
    const uint4 w0 = *(const uint4*)&xlhead[(size_t)s0 * 32 + colh];
    const uint4 w1 = *(const uint4*)&xlhead[(size_t)s1 * 32 + colh];
    h2 xh0[4], xh1[4];
    xh0[0] = u2h2(w0.x); xh0[1] = u2h2(w0.y); xh0[2] = u2h2(w0.z); xh0[3] = u2h2(w0.w);
    xh1[0] = u2h2(w1.x); xh1[1] = u2h2(w1.y); xh1[2] = u2h2(w1.z); xh1[3] = u2h2(w1.w);
    const float c0 = score(xh0);
    const float c1 = score(xh1);
    const float p0 = exp2f(c0), p1 = exp2f(c1);
    l += p0 + p1;
    const _Float16 p0h = (_Float16)p0, p1h = (_Float16)p1;
    const h2 p02 = h2{p0h, p0h}, p12 = h2{p1h, p1h};
#pragma unroll
    for (int j = 0; j < 4; ++j) acc2[j] += p02 * xh0[j] + p12 * xh1[j];
  }
  if (idx < fin) {
    const int s0 = csr[idx];
    const uint4 w0 = *(const uint4*)&xlhead[(size_t)s0 * 32 + colh];
    h2 xh0[4];
    xh0[0] = u2h2(w0.x); xh0[1] = u2h2(w0.y); xh0[2] = u2h2(w0.z); xh0[3] = u2h2(w0.w);
    const float c0 = score(xh0);
    const float p0 = exp2f(c0);
    l += p0;
    const _Float16 p0h = (_Float16)p0;
    const h2 p02 = h2{p0h, p0h};
#pragma unroll
    for (int j = 0; j < 4; ++j) acc2[j] += p02 * xh0[j];
  }
  if (valid) {
    const float rl = 1.f / (l + 1e-16f);
    float b8[8], o[8];
    *(float4*)&b8[0] = *(const float4*)&b1[col];
    *(float4*)&b8[4] = *(const float4*)&b1[col + 4];
#pragma unroll
    for (int j = 0; j < 4; ++j) {
      o[2 * j]     = (float)acc2[j][0] * rl + b8[2 * j];
      o[2 * j + 1] = (float)acc2[j][1] * rl + b8[2 * j + 1];
    }
#pragma unroll
    for (int k = 0; k < 8; ++k) o[k] = o[k] > 0.f ? o[k] : expm1f(o[k]);
    ushort4 p;
    p.x = f2h(o[0]); p.y = f2h(o[1]); p.z = f2h(o[2]); p.w = f2h(o[3]);
    ushort4 q;
    q.x = f2h(o[4]); q.y = f2h(o[5]); q.z = f2h(o[6]); q.w = f2h(o[7]);
    uint4 packed;
    packed.x = *(unsigned*)&p.x; packed.y = *(unsigned*)&p.z;
    packed.z = *(unsigned*)&q.x; packed.w = *(unsigned*)&q.z;
    *(uint4*)&hb[(size_t)n * D1 + col] = packed;
  }
}

// ---------------- Layer-2 GEMM via MFMA (fp16, no LDS) ----------------
// h2[50000, 32] = hb @ Wt2^T. B fragments direct from global (wt2 is 16 KB,
// L1-resident). No barrier.
__global__ __launch_bounds__(256) void k_gemm2m(
    const unsigned short* __restrict__ hb, const unsigned short* __restrict__ wt2,
    unsigned short* __restrict__ h2lh, float* __restrict__ h2r) {
  const int t = threadIdx.x;
  const int wave = t >> 6, lane = t & 63;
  const int fr = lane & 15, fq = lane >> 4;
  const int m0 = blockIdx.x * 128 + wave * 32;
  f32x4 acc[2][2] = {};
#pragma unroll
  for (int ks = 0; ks < 8; ++ks) {
    const int ko = ks * 32 + fq * 8;
    f16x8 a[2], b[2];
#pragma unroll
    for (int i = 0; i < 2; ++i) {
      int row = m0 + i * 16 + fr; if (row >= NN) row = NN - 1;
      a[i] = *(const f16x8*)&hb[(size_t)row * D1 + ko];
    }
#pragma unroll
    for (int j = 0; j < 2; ++j)
      b[j] = *(const f16x8*)&wt2[(j * 16 + fr) * 256 + ko];
#pragma unroll
    for (int i = 0; i < 2; ++i)
#pragma unroll
      for (int j = 0; j < 2; ++j)
        acc[i][j] = __builtin_amdgcn_mfma_f32_16x16x32_f16(a[i], b[j], acc[i][j], 0, 0, 0);
  }
#pragma unroll
  for (int i = 0; i < 2; ++i) {
    const int gm0 = m0 + i * 16 + fq * 4;
#pragma unroll
    for (int r = 0; r < 4; ++r) {
      const int gm = gm0 + r;
      if (gm < NN) {
        h2lh[(size_t)gm * C2 + fr] = f2h(acc[i][0][r]);
        h2r[(size_t)gm * C2 + fr] = acc[i][1][r];
      }
    }
  }
}

// ---------------- Layer-2 aggregation ----------------
__global__ __launch_bounds__(256) void k_agg2(
    const unsigned short* __restrict__ h2lh, const float* __restrict__ h2r,
    const int* __restrict__ offs, const unsigned short* __restrict__ csr,
    const float* __restrict__ att2, const float* __restrict__ b2,
    float* __restrict__ out) {
  const int wave = threadIdx.x >> 6;
  const int lane = threadIdx.x & 63;
  const int n = blockIdx.x * 4 + wave;
  if (n >= NN) return;
  const int c = lane & 15, g = lane >> 4;
  const float xr_v = h2r[(size_t)n * C2 + c];
  const float att_v = att2[c] * LOG2E;
  float l = 0.f, acc = 0.f;
  const int beg = offs[n], fin = offs[n + 1];
  for (int idx = beg + g; idx < fin; idx += 4) {
    int s = csr[idx];
    float xlv = h2f(h2lh[(size_t)s * C2 + c]);
    float v = xlv + xr_v;
    v = fmaxf(v, 0.2f * v);
    float sc0 = v * att_v;
    sc0 = dpp_add<0xB1>(sc0);   // xor 1 (quad_perm)
    sc0 = dpp_add<0x4E>(sc0);   // xor 2 (quad_perm)
    sc0 = dpp_add<0x124>(sc0);  // row_ror:4  -> quad totals combine
    sc0 = dpp_add<0x128>(sc0);  // row_ror:8  -> full 16-lane sum, no DS ops
    float p = exp2f(sc0);
    l += p;
    acc = fmaf(p, xlv, acc);
  }
  l += __shfl_xor(l, 16);   l += __shfl_xor(l, 32);
  acc += __shfl_xor(acc, 16); acc += __shfl_xor(acc, 32);
  float o = acc / (l + 1e-16f) + b2[c];
  o = o > 0.f ? o : 0.01f * o;
  if (lane < 16) out[(size_t)n * C2 + c] = o;
}

extern "C" void kernel_launch(void* const* d_in, const int* in_sizes, int n_in,
                              void* d_out, int out_size, void* d_ws, size_t ws_size,
                              hipStream_t stream) {
  const float* x    = (const float*)d_in[0];
  const int*   ei   = (const int*)d_in[1];
  const float* W1l  = (const float*)d_in[2];
  const float* W1r  = (const float*)d_in[3];
  const float* att1 = (const float*)d_in[4];
  const float* b1   = (const float*)d_in[5];
  const float* W2l  = (const float*)d_in[6];
  const float* W2r  = (const float*)d_in[7];
  const float* att2 = (const float*)d_in[8];
  const float* b2   = (const float*)d_in[9];
  float* out = (float*)d_out;

  // Workspace layout (~79 MB):
  unsigned short* xlh = (unsigned short*)d_ws;        // [8][NN][32] fp16
  unsigned short* xrh = xlh + (size_t)NN * D1;        // [8][NN][32] fp16
  unsigned short* hb  = xrh + (size_t)NN * D1;        // [NN][256] fp16
  int* deg  = (int*)(hb + (size_t)NN * D1);           // NN (becomes cursor)
  int* bhist = deg + NN;                              // 64 degree buckets
  int* bcur  = bhist + 64;                            // 64 bucket cursors
  int* part = bcur + 64;                              // NB
  int* offs = part + NB;                              // NN+1
  int* perm = offs + NN + 1;                          // NN degree-sorted ids
  unsigned short* csr = (unsigned short*)(perm + NN); // ET u16
  unsigned short* wt  = csr + ET + 2;                 // 512*128 fp16
  unsigned short* wt2 = wt + 512 * F1;                // 32*256 fp16
  unsigned short* h2lh = xlh;                         // alias: xlh dead after agg1
  float* h2r = (float*)(h2lh + (size_t)NN * C2);

  hipMemsetAsync(deg, 0, (NN + 64) * sizeof(int), stream);  // deg + bhist
  k_prep<<<288 + (ET + 255) / 256, 256, 0, stream>>>(
      W1l, W1r, W2l, W2r, ei, wt, wt2, deg);
  k_gemm1m<<<dim3(MPAD / 128, 4), 256, 0, stream>>>(x, wt, xlh, xrh);
  k_scan_part<<<NB, 256, 0, stream>>>(deg, part);
  k_scan_apply<<<NB, 256, 0, stream>>>(deg, part, offs, bhist);
  k_scatter<<<(ET + 255) / 256, 256, 0, stream>>>(ei, deg, csr, bhist, bcur);
  k_perm<<<NB, 256, 0, stream>>>(offs, bcur, perm);
  k_agg1<<<NBK1 * 8, 256, 0, stream>>>(xlh, xrh, hb, offs, csr, att1, b1, perm);
  k_gemm2m<<<(NN + 127) / 128, 256, 0, stream>>>(hb, wt2, h2lh, h2r);
  k_agg2<<<NN / 4, 256, 0, stream>>>(h2lh, h2r, offs, csr, att2, b2, out);
}

// Round 2
// 259.327 us; speedup vs baseline: 1.0600x; 1.0600x over previous
//
#include <hip/hip_runtime.h>
#include <math.h>

#define NN 50000
#define E0 640000
#define ET 690000   // E0 + NN self loops
#define F1 128
#define D1 256      // 8 heads * 32
#define C2 16
#define NB 196      // ceil(NN/256)
#define MPAD 50048  // 391*128, padded node count for MFMA tiles
#define PADK 136    // 128 + 8 pad (breaks ds_read_b128 bank conflicts)
#define LOG2E 1.4426950408889634f
#define NBK1 782    // ceil(NN/64) node-blocks for agg1

typedef _Float16 f16x8 __attribute__((ext_vector_type(8)));
typedef _Float16 h2 __attribute__((ext_vector_type(2)));
typedef __attribute__((ext_vector_type(4))) float f32x4;

__device__ __forceinline__ unsigned short f2h(float f) {
  union { _Float16 h; unsigned short u; } c;
  c.h = (_Float16)f;
  return c.u;
}
__device__ __forceinline__ float h2f(unsigned short u) {
  union { unsigned short u; _Float16 h; } c; c.u = u; return (float)c.h;
}
__device__ __forceinline__ h2 u2h2(unsigned u) {
  union { unsigned u; h2 h; } c; c.u = u; return c.h;
}
__device__ __forceinline__ unsigned h22u(h2 h) {
  union { h2 h; unsigned u; } c; c.h = h; return c.u;
}

// DPP-based lane-group sums: v_add_f32 with DPP modifier, no DS ops.
// 0xB1 = quad_perm [1,0,3,2] (xor 1), 0x4E = quad_perm [2,3,0,1] (xor 2),
// 0x124 = row_ror:4, 0x128 = row_ror:8 (within 16-lane row).
template <int CTRL>
__device__ __forceinline__ float dpp_add(float c) {
  int t = __builtin_amdgcn_update_dpp(0, __builtin_bit_cast(int, c), CTRL, 0xF, 0xF, true);
  return c + __builtin_bit_cast(float, t);
}

// ---------------- prep: weight converts + degree histogram ----------------
// blocks [0,256): wt | [256,288): wt2 | rest: edge histogram.
__global__ __launch_bounds__(256) void k_prep(
    const float* __restrict__ Wl, const float* __restrict__ Wr,
    const float* __restrict__ W2l, const float* __restrict__ W2r,
    const int* __restrict__ ei,
    unsigned short* __restrict__ wt, unsigned short* __restrict__ wt2,
    int* __restrict__ deg) {
  const int b = blockIdx.x;
  if (b < 256) {
    int tid = b * 256 + threadIdx.x;            // = n*128 + k
    int n = tid >> 7, k = tid & 127;
    float v = (n < 256) ? Wl[k * 256 + n] : Wr[k * 256 + (n - 256)];
    wt[tid] = f2h(v);
  } else if (b < 288) {
    int tid = (b - 256) * 256 + threadIdx.x;    // = n*256 + k
    int n = tid >> 8, k = tid & 255;
    float v = (n < 16) ? W2l[k * 16 + n] : W2r[k * 16 + (n - 16)];
    wt2[tid] = f2h(v);
  } else {
    int e = (b - 288) * 256 + threadIdx.x;
    if (e >= ET) return;
    int d = (e < E0) ? ei[E0 + e] : (e - E0);
    atomicAdd(&deg[d], 1);
  }
}

// ---------------- Layer-1 GEMM via MFMA (fp16) ----------------
// C[M=50048, N=512] = x(f32, converted in staging) @ Wt^T.
// A-tile (64 rows) staged ONCE per block; internal loop over the 4 n0
// panels re-stages B only -> x read 1x (25.6 MB) instead of 4x (102 MB).
// LDS 52 KB -> 3 blocks/CU; 782 blocks ~ 3.05/CU (balanced).
// Outputs HEAD-MAJOR: out[head][node][32].
__global__ __launch_bounds__(256) void k_gemm1m(
    const float* __restrict__ x, const unsigned short* __restrict__ wt,
    unsigned short* __restrict__ xlh, unsigned short* __restrict__ xrh) {
  __shared__ unsigned short Al[64 * PADK];
  __shared__ unsigned short Bl[128 * PADK];
  const int t = threadIdx.x;
  const int m0 = blockIdx.x * 64;
  {
    const int r = t >> 4;             // 0..15
    const int c = (t & 15) * 8;
#pragma unroll
    for (int p = 0; p < 4; ++p) {
      const int row = r + p * 16;
      const int rg = m0 + row;
      const float* xp = &x[(size_t)(rg < NN ? rg : NN - 1) * F1 + c];
      float4 lo = *(const float4*)xp;
      float4 hi = *(const float4*)(xp + 4);
      h2 q0 = h2{(_Float16)lo.x, (_Float16)lo.y};
      h2 q1 = h2{(_Float16)lo.z, (_Float16)lo.w};
      h2 q2 = h2{(_Float16)hi.x, (_Float16)hi.y};
      h2 q3 = h2{(_Float16)hi.z, (_Float16)hi.w};
      uint4 st; st.x = h22u(q0); st.y = h22u(q1); st.z = h22u(q2); st.w = h22u(q3);
      *(uint4*)&Al[row * PADK + c] = st;
    }
  }
  const int wave = t >> 6, lane = t & 63;
  const int mw = (wave >> 1) * 32, nw = (wave & 1) * 64;
  const int fr = lane & 15, fq = lane >> 4;
  for (int ny = 0; ny < 4; ++ny) {
    const int n0 = ny * 128;
    {
      const int r = t >> 4;
      const int c = (t & 15) * 8;
#pragma unroll
      for (int p = 0; p < 8; ++p) {
        const int row = r + p * 16;
        *(float4*)&Bl[row * PADK + c] = *(const float4*)&wt[(size_t)(n0 + row) * F1 + c];
      }
    }
    __syncthreads();
    f32x4 acc[2][4] = {};
#pragma unroll
    for (int ks = 0; ks < 4; ++ks) {
      const int ko = ks * 32 + fq * 8;
      f16x8 a[2], b[4];
#pragma unroll
      for (int i = 0; i < 2; ++i)
        a[i] = *(const f16x8*)&Al[(mw + i * 16 + fr) * PADK + ko];
#pragma unroll
      for (int j = 0; j < 4; ++j)
        b[j] = *(const f16x8*)&Bl[(nw + j * 16 + fr) * PADK + ko];
#pragma unroll
      for (int i = 0; i < 2; ++i)
#pragma unroll
        for (int j = 0; j < 4; ++j)
          acc[i][j] = __builtin_amdgcn_mfma_f32_16x16x32_f16(a[i], b[j], acc[i][j], 0, 0, 0);
    }
    __syncthreads();   // all waves done reading Bl before next restage
    unsigned short* outp = (n0 < 256) ? xlh : xrh;
    const int cb = (n0 & 255) + nw + fr;
#pragma unroll
    for (int j = 0; j < 4; ++j) {
      const int col = cb + j * 16;
      const int head = col >> 5, f = col & 31;
      unsigned short* hp = outp + (size_t)head * NN * 32 + f;
#pragma unroll
      for (int i = 0; i < 2; ++i) {
        const int gm0 = m0 + mw + i * 16 + fq * 4;
#pragma unroll
        for (int r = 0; r < 4; ++r) {
          const int gm = gm0 + r;
          if (gm < NN) hp[(size_t)gm * 32] = f2h(acc[i][j][r]);
        }
      }
    }
  }
}

// ---------------- CSR scan/scatter ----------------
__global__ __launch_bounds__(256) void k_scan_part(const int* __restrict__ deg,
                                                   int* __restrict__ part) {
  int i = blockIdx.x * 256 + threadIdx.x;
  int v = (i < NN) ? deg[i] : 0;
  v += __shfl_xor(v, 1);  v += __shfl_xor(v, 2);  v += __shfl_xor(v, 4);
  v += __shfl_xor(v, 8);  v += __shfl_xor(v, 16); v += __shfl_xor(v, 32);
  __shared__ int w[4];
  if ((threadIdx.x & 63) == 0) w[threadIdx.x >> 6] = v;
  __syncthreads();
  if (threadIdx.x == 0) part[blockIdx.x] = w[0] + w[1] + w[2] + w[3];
}

// Block-local scan + inline prefix over part[0..b).
__global__ __launch_bounds__(256) void k_scan_apply(int* __restrict__ deg,
                                                    const int* __restrict__ part,
                                                    int* __restrict__ offs) {
  __shared__ int lds[256];
  __shared__ int red[4];
  const int b = blockIdx.x, t = threadIdx.x;
  const int i = b * 256 + t;
  int v = (i < NN) ? deg[i] : 0;
  lds[t] = v;
  // prefix of preceding blocks' partial sums
  int pp = 0;
  for (int j = t; j < b; j += 256) pp += part[j];
  pp += __shfl_xor(pp, 1);  pp += __shfl_xor(pp, 2);  pp += __shfl_xor(pp, 4);
  pp += __shfl_xor(pp, 8);  pp += __shfl_xor(pp, 16); pp += __shfl_xor(pp, 32);
  if ((t & 63) == 0) red[t >> 6] = pp;
  __syncthreads();
  const int prefix = red[0] + red[1] + red[2] + red[3];
  for (int off = 1; off < 256; off <<= 1) {
    int u = (t >= off) ? lds[t - off] : 0;
    __syncthreads();
    lds[t] += u;
    __syncthreads();
  }
  int excl = prefix + lds[t] - v;
  if (i < NN) { offs[i] = excl; deg[i] = excl; }  // deg becomes cursor
  if (b == NB - 1 && t == 255) offs[NN] = prefix + lds[255];
}

__global__ void k_scatter(const int* __restrict__ ei, int* __restrict__ cur,
                          unsigned short* __restrict__ csr) {
  int e = blockIdx.x * 256 + threadIdx.x;
  if (e >= ET) return;
  int s, d;
  if (e < E0) { s = ei[e]; d = ei[E0 + e]; } else { s = d = e - E0; }
  int pos = atomicAdd(&cur[d], 1);
  csr[pos] = (unsigned short)s;   // node ids < 65536
}

// ---------------- Layer-1 aggregation (head-pinned, 16 nodes/wave) ----------------
// head = blockIdx&7 pins each head's 3.2 MB slice to one XCD L2 (validated
// R9/R10: FETCH 165->56 MB). One wave = 16 nodes x 1 head; each 4-lane group
// owns one node's edge loop; p group-uniform -> no epilogue reduction.
// Edge loop unrolled 4-wide with clamped software prefetch: next quad's
// csr ids + xl vectors are issued before computing the current quad ->
// 8 loads in flight per group instead of 2 (attacks the csr->xl dependent
// L2-latency chain, the R0 bottleneck).
__global__ __launch_bounds__(256) void k_agg1(
    const unsigned short* __restrict__ xlh, const unsigned short* __restrict__ xrh,
    unsigned short* __restrict__ hb,
    const int* __restrict__ offs, const unsigned short* __restrict__ csr,
    const float* __restrict__ att, const float* __restrict__ b1) {
  const int b = blockIdx.x;
  const int head = b & 7;
  const int wave = threadIdx.x >> 6;
  const int lane = threadIdx.x & 63;
  const int g = lane >> 2;          // node group 0..15
  const int j4 = lane & 3;          // lane within group
  const int idxn = (b >> 3) * 64 + wave * 16 + g;
  const bool valid = idxn < NN;
  const int n = valid ? idxn : 0;
  const int colh = j4 * 8;          // feat offset within head
  const int col = head * 32 + colh; // global feat col (att/b1)
  const unsigned short* xlhead = xlh + (size_t)head * NN * 32;

  const uint4 xru = *(const uint4*)&xrh[((size_t)head * NN + n) * 32 + colh];
  h2 xr2[4];
  xr2[0] = u2h2(xru.x); xr2[1] = u2h2(xru.y);
  xr2[2] = u2h2(xru.z); xr2[3] = u2h2(xru.w);
  float at8[8];
  *(float4*)&at8[0] = *(const float4*)&att[col];
  *(float4*)&at8[4] = *(const float4*)&att[col + 4];
  h2 ath6[4], ath4[4];
#pragma unroll
  for (int j = 0; j < 4; ++j) {
    ath6[j] = h2{(_Float16)(at8[2 * j] * (0.6f * LOG2E)),
                 (_Float16)(at8[2 * j + 1] * (0.6f * LOG2E))};
    ath4[j] = h2{(_Float16)(at8[2 * j] * (0.4f * LOG2E)),
                 (_Float16)(at8[2 * j + 1] * (0.4f * LOG2E))};
  }
  float l = 0.f;
  h2 acc2[4] = {h2{0, 0}, h2{0, 0}, h2{0, 0}, h2{0, 0}};
  const int beg = valid ? offs[n] : 0;
  const int fin = valid ? offs[n + 1] : 0;

  auto XL = [&](int s) -> uint4 {
    return *(const uint4*)&xlhead[(size_t)s * 32 + colh];
  };
  auto edge = [&](const uint4& w) {
    h2 xh[4];
    xh[0] = u2h2(w.x); xh[1] = u2h2(w.y); xh[2] = u2h2(w.z); xh[3] = u2h2(w.w);
    float cv = 0.f, ca = 0.f;
#pragma unroll
    for (int j = 0; j < 4; ++j) {
      h2 v = xh[j] + xr2[j];
      h2 a = u2h2(h22u(v) & 0x7FFF7FFFu);       // |v| per half
      cv = __builtin_amdgcn_fdot2(v, ath6[j], cv, false);
      ca = __builtin_amdgcn_fdot2(a, ath4[j], ca, false);
    }
    float c = cv + ca;
    c = dpp_add<0xB1>(c);             // + lane^1 (quad_perm, no DS op)
    c = dpp_add<0x4E>(c);             // + lane^2 -> group total in all 4 lanes
    const float p = exp2f(c);
    l += p;
    const _Float16 ph = (_Float16)p;
    const h2 p2 = h2{ph, ph};
#pragma unroll
    for (int j = 0; j < 4; ++j) acc2[j] += p2 * xh[j];
  };

  int idx = beg;
  if (idx + 3 < fin) {
    int s0 = csr[idx], s1 = csr[idx + 1], s2 = csr[idx + 2], s3 = csr[idx + 3];
    uint4 w0 = XL(s0), w1 = XL(s1), w2 = XL(s2), w3 = XL(s3);
    for (;;) {
      const int nx = idx + 4;
      const bool more = nx + 3 < fin;
      // clamped prefetch of the next quad (wasted only on the final iter;
      // clamp target beg is always a valid, L2-hot edge)
      const int b0 = more ? nx : beg;
      const int b1i = more ? nx + 1 : beg;
      const int b2i = more ? nx + 2 : beg;
      const int b3i = more ? nx + 3 : beg;
      const int t0 = csr[b0], t1 = csr[b1i], t2 = csr[b2i], t3 = csr[b3i];
      const uint4 v0 = XL(t0), v1 = XL(t1), v2 = XL(t2), v3 = XL(t3);
      edge(w0); edge(w1); edge(w2); edge(w3);
      idx = nx;
      if (!more) break;
      w0 = v0; w1 = v1; w2 = v2; w3 = v3;
    }
  }
  for (; idx < fin; ++idx) {          // tail: <=3 edges
    const int s = csr[idx];
    const uint4 w = XL(s);
    edge(w);
  }

  if (valid) {
    const float rl = 1.f / (l + 1e-16f);
    float b8[8], o[8];
    *(float4*)&b8[0] = *(const float4*)&b1[col];
    *(float4*)&b8[4] = *(const float4*)&b1[col + 4];
#pragma unroll
    for (int j = 0; j < 4; ++j) {
      o[2 * j]     = (float)acc2[j][0] * rl + b8[2 * j];
      o[2 * j + 1] = (float)acc2[j][1] * rl + b8[2 * j + 1];
    }
#pragma unroll
    for (int k = 0; k < 8; ++k) o[k] = o[k] > 0.f ? o[k] : expm1f(o[k]);
    ushort4 p;
    p.x = f2h(o[0]); p.y = f2h(o[1]); p.z = f2h(o[2]); p.w = f2h(o[3]);
    ushort4 q;
    q.x = f2h(o[4]); q.y = f2h(o[5]); q.z = f2h(o[6]); q.w = f2h(o[7]);
    uint4 packed;
    packed.x = *(unsigned*)&p.x; packed.y = *(unsigned*)&p.z;
    packed.z = *(unsigned*)&q.x; packed.w = *(unsigned*)&q.z;
    *(uint4*)&hb[(size_t)n * D1 + col] = packed;
  }
}

// ---------------- Layer-2 GEMM via MFMA (fp16, no LDS) ----------------
// h2[50000, 32] = hb @ Wt2^T. B fragments direct from global (wt2 is 16 KB,
// L1-resident). No barrier.
__global__ __launch_bounds__(256) void k_gemm2m(
    const unsigned short* __restrict__ hb, const unsigned short* __restrict__ wt2,
    unsigned short* __restrict__ h2lh, float* __restrict__ h2r) {
  const int t = threadIdx.x;
  const int wave = t >> 6, lane = t & 63;
  const int fr = lane & 15, fq = lane >> 4;
  const int m0 = blockIdx.x * 128 + wave * 32;
  f32x4 acc[2][2] = {};
#pragma unroll
  for (int ks = 0; ks < 8; ++ks) {
    const int ko = ks * 32 + fq * 8;
    f16x8 a[2], b[2];
#pragma unroll
    for (int i = 0; i < 2; ++i) {
      int row = m0 + i * 16 + fr; if (row >= NN) row = NN - 1;
      a[i] = *(const f16x8*)&hb[(size_t)row * D1 + ko];
    }
#pragma unroll
    for (int j = 0; j < 2; ++j)
      b[j] = *(const f16x8*)&wt2[(j * 16 + fr) * 256 + ko];
#pragma unroll
    for (int i = 0; i < 2; ++i)
#pragma unroll
      for (int j = 0; j < 2; ++j)
        acc[i][j] = __builtin_amdgcn_mfma_f32_16x16x32_f16(a[i], b[j], acc[i][j], 0, 0, 0);
  }
#pragma unroll
  for (int i = 0; i < 2; ++i) {
    const int gm0 = m0 + i * 16 + fq * 4;
#pragma unroll
    for (int r = 0; r < 4; ++r) {
      const int gm = gm0 + r;
      if (gm < NN) {
        h2lh[(size_t)gm * C2 + fr] = f2h(acc[i][0][r]);
        h2r[(size_t)gm * C2 + fr] = acc[i][1][r];
      }
    }
  }
}

// ---------------- Layer-2 aggregation ----------------
// Unrolled 2-wide (8 edges/wave-iter) so both gathers are in flight together.
__global__ __launch_bounds__(256) void k_agg2(
    const unsigned short* __restrict__ h2lh, const float* __restrict__ h2r,
    const int* __restrict__ offs, const unsigned short* __restrict__ csr,
    const float* __restrict__ att2, const float* __restrict__ b2,
    float* __restrict__ out) {
  const int wave = threadIdx.x >> 6;
  const int lane = threadIdx.x & 63;
  const int n = blockIdx.x * 4 + wave;
  if (n >= NN) return;
  const int c = lane & 15, g = lane >> 4;
  const float xr_v = h2r[(size_t)n * C2 + c];
  const float att_v = att2[c] * LOG2E;
  float l = 0.f, acc = 0.f;
  const int beg = offs[n], fin = offs[n + 1];
  for (int idx = beg + g; idx < fin; idx += 8) {
    const int i1 = idx + 4;
    const bool m1 = i1 < fin;
    const int s0 = csr[idx];
    const int s1 = csr[m1 ? i1 : idx];
    const float xl0 = h2f(h2lh[(size_t)s0 * C2 + c]);
    const float xl1 = h2f(h2lh[(size_t)s1 * C2 + c]);
    float v0 = xl0 + xr_v; v0 = fmaxf(v0, 0.2f * v0);
    float v1 = xl1 + xr_v; v1 = fmaxf(v1, 0.2f * v1);
    float sc0 = v0 * att_v, sc1 = v1 * att_v;
    sc0 = dpp_add<0xB1>(sc0);   sc1 = dpp_add<0xB1>(sc1);
    sc0 = dpp_add<0x4E>(sc0);   sc1 = dpp_add<0x4E>(sc1);
    sc0 = dpp_add<0x124>(sc0);  sc1 = dpp_add<0x124>(sc1);
    sc0 = dpp_add<0x128>(sc0);  sc1 = dpp_add<0x128>(sc1);
    const float p0 = exp2f(sc0);
    const float p1 = m1 ? exp2f(sc1) : 0.f;
    l += p0 + p1;
    acc = fmaf(p0, xl0, fmaf(p1, xl1, acc));
  }
  l += __shfl_xor(l, 16);   l += __shfl_xor(l, 32);
  acc += __shfl_xor(acc, 16); acc += __shfl_xor(acc, 32);
  float o = acc / (l + 1e-16f) + b2[c];
  o = o > 0.f ? o : 0.01f * o;
  if (lane < 16) out[(size_t)n * C2 + c] = o;
}

extern "C" void kernel_launch(void* const* d_in, const int* in_sizes, int n_in,
                              void* d_out, int out_size, void* d_ws, size_t ws_size,
                              hipStream_t stream) {
  const float* x    = (const float*)d_in[0];
  const int*   ei   = (const int*)d_in[1];
  const float* W1l  = (const float*)d_in[2];
  const float* W1r  = (const float*)d_in[3];
  const float* att1 = (const float*)d_in[4];
  const float* b1   = (const float*)d_in[5];
  const float* W2l  = (const float*)d_in[6];
  const float* W2r  = (const float*)d_in[7];
  const float* att2 = (const float*)d_in[8];
  const float* b2   = (const float*)d_in[9];
  float* out = (float*)d_out;

  // Workspace layout (~79 MB):
  unsigned short* xlh = (unsigned short*)d_ws;        // [8][NN][32] fp16
  unsigned short* xrh = xlh + (size_t)NN * D1;        // [8][NN][32] fp16
  unsigned short* hb  = xrh + (size_t)NN * D1;        // [NN][256] fp16
  int* deg  = (int*)(hb + (size_t)NN * D1);           // NN (becomes cursor)
  int* part = deg + NN;                               // NB
  int* offs = part + NB;                              // NN+1
  unsigned short* csr = (unsigned short*)(offs + NN + 1);  // ET u16
  unsigned short* wt  = csr + ET + 2;                 // 512*128 fp16
  unsigned short* wt2 = wt + 512 * F1;                // 32*256 fp16
  unsigned short* h2lh = xlh;                         // alias: xlh dead after agg1
  float* h2r = (float*)(h2lh + (size_t)NN * C2);

  hipMemsetAsync(deg, 0, NN * sizeof(int), stream);
  k_prep<<<288 + (ET + 255) / 256, 256, 0, stream>>>(
      W1l, W1r, W2l, W2r, ei, wt, wt2, deg);
  k_gemm1m<<<MPAD / 64, 256, 0, stream>>>(x, wt, xlh, xrh);
  k_scan_part<<<NB, 256, 0, stream>>>(deg, part);
  k_scan_apply<<<NB, 256, 0, stream>>>(deg, part, offs);
  k_scatter<<<(ET + 255) / 256, 256, 0, stream>>>(ei, deg, csr);
  k_agg1<<<NBK1 * 8, 256, 0, stream>>>(xlh, xrh, hb, offs, csr, att1, b1);
  k_gemm2m<<<(NN + 127) / 128, 256, 0, stream>>>(hb, wt2, h2lh, h2r);
  k_agg2<<<NN / 4, 256, 0, stream>>>(h2lh, h2r, offs, csr, att2, b2, out);
}

// Round 3
// 256.882 us; speedup vs baseline: 1.0701x; 1.0095x over previous
//
#include <hip/hip_runtime.h>
#include <math.h>

#define NN 50000
#define E0 640000
#define ET 690000   // E0 + NN self loops
#define F1 128
#define D1 256      // 8 heads * 32
#define C2 16
#define NB 196      // ceil(NN/256)
#define MPAD 50048  // 391*128, padded node count for MFMA tiles
#define PADK 136    // 128 + 8 pad (breaks ds_read_b128 bank conflicts)
#define LOG2E 1.4426950408889634f
#define NBK1 782    // ceil(NN/64) node-blocks for agg1

typedef _Float16 f16x8 __attribute__((ext_vector_type(8)));
typedef _Float16 h2 __attribute__((ext_vector_type(2)));
typedef __attribute__((ext_vector_type(4))) float f32x4;

__device__ __forceinline__ unsigned short f2h(float f) {
  union { _Float16 h; unsigned short u; } c;
  c.h = (_Float16)f;
  return c.u;
}
__device__ __forceinline__ float h2f(unsigned short u) {
  union { unsigned short u; _Float16 h; } c; c.u = u; return (float)c.h;
}
__device__ __forceinline__ h2 u2h2(unsigned u) {
  union { unsigned u; h2 h; } c; c.u = u; return c.h;
}
__device__ __forceinline__ unsigned h22u(h2 h) {
  union { h2 h; unsigned u; } c; c.h = h; return c.u;
}

// DPP-based lane-group sums: v_add_f32 with DPP modifier, no DS ops.
// 0xB1 = quad_perm [1,0,3,2] (xor 1), 0x4E = quad_perm [2,3,0,1] (xor 2),
// 0x124 = row_ror:4, 0x128 = row_ror:8 (within 16-lane row).
template <int CTRL>
__device__ __forceinline__ float dpp_add(float c) {
  int t = __builtin_amdgcn_update_dpp(0, __builtin_bit_cast(int, c), CTRL, 0xF, 0xF, true);
  return c + __builtin_bit_cast(float, t);
}
// Broadcast lane K of each quad to all 4 lanes of the quad (quad_perm K,K,K,K).
template <int K>
__device__ __forceinline__ int dpp_bcast(int v) {
  constexpr int ctrl = K | (K << 2) | (K << 4) | (K << 6);
  return __builtin_amdgcn_update_dpp(0, v, ctrl, 0xF, 0xF, true);
}

// ---------------- prep: weight converts + degree histogram ----------------
// blocks [0,256): wt | [256,288): wt2 | rest: edge histogram.
__global__ __launch_bounds__(256) void k_prep(
    const float* __restrict__ Wl, const float* __restrict__ Wr,
    const float* __restrict__ W2l, const float* __restrict__ W2r,
    const int* __restrict__ ei,
    unsigned short* __restrict__ wt, unsigned short* __restrict__ wt2,
    int* __restrict__ deg) {
  const int b = blockIdx.x;
  if (b < 256) {
    int tid = b * 256 + threadIdx.x;            // = n*128 + k
    int n = tid >> 7, k = tid & 127;
    float v = (n < 256) ? Wl[k * 256 + n] : Wr[k * 256 + (n - 256)];
    wt[tid] = f2h(v);
  } else if (b < 288) {
    int tid = (b - 256) * 256 + threadIdx.x;    // = n*256 + k
    int n = tid >> 8, k = tid & 255;
    float v = (n < 16) ? W2l[k * 16 + n] : W2r[k * 16 + (n - 16)];
    wt2[tid] = f2h(v);
  } else {
    int e = (b - 288) * 256 + threadIdx.x;
    if (e >= ET) return;
    int d = (e < E0) ? ei[E0 + e] : (e - E0);
    atomicAdd(&deg[d], 1);
  }
}

// ---------------- Layer-1 GEMM via MFMA (fp16) ----------------
// C[M=50048, N=512] = x(f32, converted in staging) @ Wt^T.
// A-tile (64 rows) staged ONCE per block; internal loop over the 4 n0
// panels re-stages B only -> x read 1x (25.6 MB) instead of 4x (102 MB).
// Outputs HEAD-MAJOR: out[head][node][32].
__global__ __launch_bounds__(256) void k_gemm1m(
    const float* __restrict__ x, const unsigned short* __restrict__ wt,
    unsigned short* __restrict__ xlh, unsigned short* __restrict__ xrh) {
  __shared__ unsigned short Al[64 * PADK];
  __shared__ unsigned short Bl[128 * PADK];
  const int t = threadIdx.x;
  const int m0 = blockIdx.x * 64;
  {
    const int r = t >> 4;             // 0..15
    const int c = (t & 15) * 8;
#pragma unroll
    for (int p = 0; p < 4; ++p) {
      const int row = r + p * 16;
      const int rg = m0 + row;
      const float* xp = &x[(size_t)(rg < NN ? rg : NN - 1) * F1 + c];
      float4 lo = *(const float4*)xp;
      float4 hi = *(const float4*)(xp + 4);
      h2 q0 = h2{(_Float16)lo.x, (_Float16)lo.y};
      h2 q1 = h2{(_Float16)lo.z, (_Float16)lo.w};
      h2 q2 = h2{(_Float16)hi.x, (_Float16)hi.y};
      h2 q3 = h2{(_Float16)hi.z, (_Float16)hi.w};
      uint4 st; st.x = h22u(q0); st.y = h22u(q1); st.z = h22u(q2); st.w = h22u(q3);
      *(uint4*)&Al[row * PADK + c] = st;
    }
  }
  const int wave = t >> 6, lane = t & 63;
  const int mw = (wave >> 1) * 32, nw = (wave & 1) * 64;
  const int fr = lane & 15, fq = lane >> 4;
  for (int ny = 0; ny < 4; ++ny) {
    const int n0 = ny * 128;
    {
      const int r = t >> 4;
      const int c = (t & 15) * 8;
#pragma unroll
      for (int p = 0; p < 8; ++p) {
        const int row = r + p * 16;
        *(float4*)&Bl[row * PADK + c] = *(const float4*)&wt[(size_t)(n0 + row) * F1 + c];
      }
    }
    __syncthreads();
    f32x4 acc[2][4] = {};
#pragma unroll
    for (int ks = 0; ks < 4; ++ks) {
      const int ko = ks * 32 + fq * 8;
      f16x8 a[2], b[4];
#pragma unroll
      for (int i = 0; i < 2; ++i)
        a[i] = *(const f16x8*)&Al[(mw + i * 16 + fr) * PADK + ko];
#pragma unroll
      for (int j = 0; j < 4; ++j)
        b[j] = *(const f16x8*)&Bl[(nw + j * 16 + fr) * PADK + ko];
#pragma unroll
      for (int i = 0; i < 2; ++i)
#pragma unroll
        for (int j = 0; j < 4; ++j)
          acc[i][j] = __builtin_amdgcn_mfma_f32_16x16x32_f16(a[i], b[j], acc[i][j], 0, 0, 0);
    }
    __syncthreads();   // all waves done reading Bl before next restage
    unsigned short* outp = (n0 < 256) ? xlh : xrh;
    const int cb = (n0 & 255) + nw + fr;
#pragma unroll
    for (int j = 0; j < 4; ++j) {
      const int col = cb + j * 16;
      const int head = col >> 5, f = col & 31;
      unsigned short* hp = outp + (size_t)head * NN * 32 + f;
#pragma unroll
      for (int i = 0; i < 2; ++i) {
        const int gm0 = m0 + mw + i * 16 + fq * 4;
#pragma unroll
        for (int r = 0; r < 4; ++r) {
          const int gm = gm0 + r;
          if (gm < NN) hp[(size_t)gm * 32] = f2h(acc[i][j][r]);
        }
      }
    }
  }
}

// ---------------- CSR scan/scatter ----------------
__global__ __launch_bounds__(256) void k_scan_part(const int* __restrict__ deg,
                                                   int* __restrict__ part) {
  int i = blockIdx.x * 256 + threadIdx.x;
  int v = (i < NN) ? deg[i] : 0;
  v += __shfl_xor(v, 1);  v += __shfl_xor(v, 2);  v += __shfl_xor(v, 4);
  v += __shfl_xor(v, 8);  v += __shfl_xor(v, 16); v += __shfl_xor(v, 32);
  __shared__ int w[4];
  if ((threadIdx.x & 63) == 0) w[threadIdx.x >> 6] = v;
  __syncthreads();
  if (threadIdx.x == 0) part[blockIdx.x] = w[0] + w[1] + w[2] + w[3];
}

// Block-local scan + inline prefix over part[0..b).
__global__ __launch_bounds__(256) void k_scan_apply(int* __restrict__ deg,
                                                    const int* __restrict__ part,
                                                    int* __restrict__ offs) {
  __shared__ int lds[256];
  __shared__ int red[4];
  const int b = blockIdx.x, t = threadIdx.x;
  const int i = b * 256 + t;
  int v = (i < NN) ? deg[i] : 0;
  lds[t] = v;
  // prefix of preceding blocks' partial sums
  int pp = 0;
  for (int j = t; j < b; j += 256) pp += part[j];
  pp += __shfl_xor(pp, 1);  pp += __shfl_xor(pp, 2);  pp += __shfl_xor(pp, 4);
  pp += __shfl_xor(pp, 8);  pp += __shfl_xor(pp, 16); pp += __shfl_xor(pp, 32);
  if ((t & 63) == 0) red[t >> 6] = pp;
  __syncthreads();
  const int prefix = red[0] + red[1] + red[2] + red[3];
  for (int off = 1; off < 256; off <<= 1) {
    int u = (t >= off) ? lds[t - off] : 0;
    __syncthreads();
    lds[t] += u;
    __syncthreads();
  }
  int excl = prefix + lds[t] - v;
  if (i < NN) { offs[i] = excl; deg[i] = excl; }  // deg becomes cursor
  if (b == NB - 1 && t == 255) offs[NN] = prefix + lds[255];
}

__global__ void k_scatter(const int* __restrict__ ei, int* __restrict__ cur,
                          unsigned short* __restrict__ csr) {
  int e = blockIdx.x * 256 + threadIdx.x;
  if (e >= ET) return;
  int s, d;
  if (e < E0) { s = ei[e]; d = ei[E0 + e]; } else { s = d = e - E0; }
  int pos = atomicAdd(&cur[d], 1);
  csr[pos] = (unsigned short)s;   // node ids < 65536
}

// ---------------- Layer-1 aggregation (head-pinned, 16 nodes/wave) ----------------
// head = blockIdx&7 pins each head's 3.2 MB slice to one XCD L2 (FETCH ~53 MB
// = compulsory). One wave = 16 nodes x 1 head; each 4-lane group owns one
// node's edge loop; p group-uniform -> no epilogue reduction.
// Pipeline (R3): csr ids are LANE-SPLIT (lane j4 loads csr[idx+j4], 1 VMEM
// per quad) and kept TWO quads ahead; ids broadcast to the group via free
// DPP quad_perm; XL gathers issued ONE quad ahead from resident ids. No
// intra-iteration csr->XL dependency -> the only waitcnt is at loop-back,
// a full compute body after issue. Tail handled by cndmask masking (p=0).
__global__ __launch_bounds__(256) void k_agg1(
    const unsigned short* __restrict__ xlh, const unsigned short* __restrict__ xrh,
    unsigned short* __restrict__ hb,
    const int* __restrict__ offs, const unsigned short* __restrict__ csr,
    const float* __restrict__ att, const float* __restrict__ b1) {
  const int b = blockIdx.x;
  const int head = b & 7;
  const int wave = threadIdx.x >> 6;
  const int lane = threadIdx.x & 63;
  const int g = lane >> 2;          // node group 0..15
  const int j4 = lane & 3;          // lane within group
  const int idxn = (b >> 3) * 64 + wave * 16 + g;
  const bool valid = idxn < NN;
  const int n = valid ? idxn : 0;
  const int colh = j4 * 8;          // feat offset within head
  const int col = head * 32 + colh; // global feat col (att/b1)
  const unsigned short* xlhead = xlh + (size_t)head * NN * 32;

  const uint4 xru = *(const uint4*)&xrh[((size_t)head * NN + n) * 32 + colh];
  h2 xr2[4];
  xr2[0] = u2h2(xru.x); xr2[1] = u2h2(xru.y);
  xr2[2] = u2h2(xru.z); xr2[3] = u2h2(xru.w);
  float at8[8];
  *(float4*)&at8[0] = *(const float4*)&att[col];
  *(float4*)&at8[4] = *(const float4*)&att[col + 4];
  h2 ath6[4], ath4[4];
#pragma unroll
  for (int j = 0; j < 4; ++j) {
    ath6[j] = h2{(_Float16)(at8[2 * j] * (0.6f * LOG2E)),
                 (_Float16)(at8[2 * j + 1] * (0.6f * LOG2E))};
    ath4[j] = h2{(_Float16)(at8[2 * j] * (0.4f * LOG2E)),
                 (_Float16)(at8[2 * j + 1] * (0.4f * LOG2E))};
  }
  float l = 0.f;
  h2 acc2[4] = {h2{0, 0}, h2{0, 0}, h2{0, 0}, h2{0, 0}};
  const int beg = valid ? offs[n] : 0;
  const int fin = valid ? offs[n + 1] : 0;

  // lane-split id load: lane j4 fetches csr[base+j4], clamped into [beg,fin)
  auto ldids = [&](int base) -> int {
    int a = base + j4;
    a = (a < fin) ? a : beg;      // empty groups (beg==fin==0) read csr[0]
    return (int)csr[a];
  };
  auto XLrow = [&](int s) -> uint4 {
    return *(const uint4*)&xlhead[(size_t)s * 32 + colh];
  };
  auto edge = [&](const uint4& w, bool live) {
    h2 xh[4];
    xh[0] = u2h2(w.x); xh[1] = u2h2(w.y); xh[2] = u2h2(w.z); xh[3] = u2h2(w.w);
    float cv = 0.f, ca = 0.f;
#pragma unroll
    for (int j = 0; j < 4; ++j) {
      h2 v = xh[j] + xr2[j];
      h2 a = u2h2(h22u(v) & 0x7FFF7FFFu);       // |v| per half
      cv = __builtin_amdgcn_fdot2(v, ath6[j], cv, false);
      ca = __builtin_amdgcn_fdot2(a, ath4[j], ca, false);
    }
    float c = cv + ca;
    c = dpp_add<0xB1>(c);             // + lane^1 (quad_perm, no DS op)
    c = dpp_add<0x4E>(c);             // + lane^2 -> group total in all 4 lanes
    float p = exp2f(c);
    p = live ? p : 0.f;
    l += p;
    const _Float16 ph = (_Float16)p;
    const h2 p2 = h2{ph, ph};
#pragma unroll
    for (int j = 0; j < 4; ++j) acc2[j] += p2 * xh[j];
  };

  // software pipeline: w = quad idx, ids1 = ids for quad idx+4
  int ids = ldids(beg);
  uint4 w0 = XLrow(dpp_bcast<0>(ids));
  uint4 w1 = XLrow(dpp_bcast<1>(ids));
  uint4 w2 = XLrow(dpp_bcast<2>(ids));
  uint4 w3 = XLrow(dpp_bcast<3>(ids));
  int ids1 = ldids(beg + 4);
  for (int idx = beg; idx < fin; idx += 4) {
    const uint4 v0 = XLrow(dpp_bcast<0>(ids1));   // gathers for quad idx+4
    const uint4 v1 = XLrow(dpp_bcast<1>(ids1));
    const uint4 v2 = XLrow(dpp_bcast<2>(ids1));
    const uint4 v3 = XLrow(dpp_bcast<3>(ids1));
    const int ids2 = ldids(idx + 8);              // ids for quad idx+8
    edge(w0, true);                               // idx < fin by loop cond
    edge(w1, idx + 1 < fin);
    edge(w2, idx + 2 < fin);
    edge(w3, idx + 3 < fin);
    w0 = v0; w1 = v1; w2 = v2; w3 = v3; ids1 = ids2;
  }

  if (valid) {
    const float rl = __builtin_amdgcn_rcpf(l + 1e-16f);
    float b8[8], o[8];
    *(float4*)&b8[0] = *(const float4*)&b1[col];
    *(float4*)&b8[4] = *(const float4*)&b1[col + 4];
#pragma unroll
    for (int j = 0; j < 4; ++j) {
      o[2 * j]     = (float)acc2[j][0] * rl + b8[2 * j];
      o[2 * j + 1] = (float)acc2[j][1] * rl + b8[2 * j + 1];
    }
#pragma unroll
    for (int k = 0; k < 8; ++k)
      o[k] = o[k] > 0.f ? o[k] : exp2f(o[k] * LOG2E) - 1.f;  // cheap ELU
    ushort4 p;
    p.x = f2h(o[0]); p.y = f2h(o[1]); p.z = f2h(o[2]); p.w = f2h(o[3]);
    ushort4 q;
    q.x = f2h(o[4]); q.y = f2h(o[5]); q.z = f2h(o[6]); q.w = f2h(o[7]);
    uint4 packed;
    packed.x = *(unsigned*)&p.x; packed.y = *(unsigned*)&p.z;
    packed.z = *(unsigned*)&q.x; packed.w = *(unsigned*)&q.z;
    *(uint4*)&hb[(size_t)n * D1 + col] = packed;
  }
}

// ---------------- Layer-2 GEMM via MFMA (fp16, no LDS) ----------------
// h2[50000, 32] = hb @ Wt2^T. B fragments direct from global (wt2 is 16 KB,
// L1-resident). No barrier.
__global__ __launch_bounds__(256) void k_gemm2m(
    const unsigned short* __restrict__ hb, const unsigned short* __restrict__ wt2,
    unsigned short* __restrict__ h2lh, float* __restrict__ h2r) {
  const int t = threadIdx.x;
  const int wave = t >> 6, lane = t & 63;
  const int fr = lane & 15, fq = lane >> 4;
  const int m0 = blockIdx.x * 128 + wave * 32;
  f32x4 acc[2][2] = {};
#pragma unroll
  for (int ks = 0; ks < 8; ++ks) {
    const int ko = ks * 32 + fq * 8;
    f16x8 a[2], b[2];
#pragma unroll
    for (int i = 0; i < 2; ++i) {
      int row = m0 + i * 16 + fr; if (row >= NN) row = NN - 1;
      a[i] = *(const f16x8*)&hb[(size_t)row * D1 + ko];
    }
#pragma unroll
    for (int j = 0; j < 2; ++j)
      b[j] = *(const f16x8*)&wt2[(j * 16 + fr) * 256 + ko];
#pragma unroll
    for (int i = 0; i < 2; ++i)
#pragma unroll
      for (int j = 0; j < 2; ++j)
        acc[i][j] = __builtin_amdgcn_mfma_f32_16x16x32_f16(a[i], b[j], acc[i][j], 0, 0, 0);
  }
#pragma unroll
  for (int i = 0; i < 2; ++i) {
    const int gm0 = m0 + i * 16 + fq * 4;
#pragma unroll
    for (int r = 0; r < 4; ++r) {
      const int gm = gm0 + r;
      if (gm < NN) {
        h2lh[(size_t)gm * C2 + fr] = f2h(acc[i][0][r]);
        h2r[(size_t)gm * C2 + fr] = acc[i][1][r];
      }
    }
  }
}

// ---------------- Layer-2 aggregation ----------------
// Unrolled 2-wide (8 edges/wave-iter) so both gathers are in flight together.
__global__ __launch_bounds__(256) void k_agg2(
    const unsigned short* __restrict__ h2lh, const float* __restrict__ h2r,
    const int* __restrict__ offs, const unsigned short* __restrict__ csr,
    const float* __restrict__ att2, const float* __restrict__ b2,
    float* __restrict__ out) {
  const int wave = threadIdx.x >> 6;
  const int lane = threadIdx.x & 63;
  const int n = blockIdx.x * 4 + wave;
  if (n >= NN) return;
  const int c = lane & 15, g = lane >> 4;
  const float xr_v = h2r[(size_t)n * C2 + c];
  const float att_v = att2[c] * LOG2E;
  float l = 0.f, acc = 0.f;
  const int beg = offs[n], fin = offs[n + 1];
  for (int idx = beg + g; idx < fin; idx += 8) {
    const int i1 = idx + 4;
    const bool m1 = i1 < fin;
    const int s0 = csr[idx];
    const int s1 = csr[m1 ? i1 : idx];
    const float xl0 = h2f(h2lh[(size_t)s0 * C2 + c]);
    const float xl1 = h2f(h2lh[(size_t)s1 * C2 + c]);
    float v0 = xl0 + xr_v; v0 = fmaxf(v0, 0.2f * v0);
    float v1 = xl1 + xr_v; v1 = fmaxf(v1, 0.2f * v1);
    float sc0 = v0 * att_v, sc1 = v1 * att_v;
    sc0 = dpp_add<0xB1>(sc0);   sc1 = dpp_add<0xB1>(sc1);
    sc0 = dpp_add<0x4E>(sc0);   sc1 = dpp_add<0x4E>(sc1);
    sc0 = dpp_add<0x124>(sc0);  sc1 = dpp_add<0x124>(sc1);
    sc0 = dpp_add<0x128>(sc0);  sc1 = dpp_add<0x128>(sc1);
    const float p0 = exp2f(sc0);
    const float p1 = m1 ? exp2f(sc1) : 0.f;
    l += p0 + p1;
    acc = fmaf(p0, xl0, fmaf(p1, xl1, acc));
  }
  l += __shfl_xor(l, 16);   l += __shfl_xor(l, 32);
  acc += __shfl_xor(acc, 16); acc += __shfl_xor(acc, 32);
  float o = acc * __builtin_amdgcn_rcpf(l + 1e-16f) + b2[c];
  o = o > 0.f ? o : 0.01f * o;
  if (lane < 16) out[(size_t)n * C2 + c] = o;
}

extern "C" void kernel_launch(void* const* d_in, const int* in_sizes, int n_in,
                              void* d_out, int out_size, void* d_ws, size_t ws_size,
                              hipStream_t stream) {
  const float* x    = (const float*)d_in[0];
  const int*   ei   = (const int*)d_in[1];
  const float* W1l  = (const float*)d_in[2];
  const float* W1r  = (const float*)d_in[3];
  const float* att1 = (const float*)d_in[4];
  const float* b1   = (const float*)d_in[5];
  const float* W2l  = (const float*)d_in[6];
  const float* W2r  = (const float*)d_in[7];
  const float* att2 = (const float*)d_in[8];
  const float* b2   = (const float*)d_in[9];
  float* out = (float*)d_out;

  // Workspace layout (~79 MB):
  unsigned short* xlh = (unsigned short*)d_ws;        // [8][NN][32] fp16
  unsigned short* xrh = xlh + (size_t)NN * D1;        // [8][NN][32] fp16
  unsigned short* hb  = xrh + (size_t)NN * D1;        // [NN][256] fp16
  int* deg  = (int*)(hb + (size_t)NN * D1);           // NN (becomes cursor)
  int* part = deg + NN;                               // NB
  int* offs = part + NB;                              // NN+1
  unsigned short* csr = (unsigned short*)(offs + NN + 1);  // ET u16
  unsigned short* wt  = csr + ET + 2;                 // 512*128 fp16
  unsigned short* wt2 = wt + 512 * F1;                // 32*256 fp16
  unsigned short* h2lh = xlh;                         // alias: xlh dead after agg1
  float* h2r = (float*)(h2lh + (size_t)NN * C2);

  hipMemsetAsync(deg, 0, NN * sizeof(int), stream);
  k_prep<<<288 + (ET + 255) / 256, 256, 0, stream>>>(
      W1l, W1r, W2l, W2r, ei, wt, wt2, deg);
  k_gemm1m<<<MPAD / 64, 256, 0, stream>>>(x, wt, xlh, xrh);
  k_scan_part<<<NB, 256, 0, stream>>>(deg, part);
  k_scan_apply<<<NB, 256, 0, stream>>>(deg, part, offs);
  k_scatter<<<(ET + 255) / 256, 256, 0, stream>>>(ei, deg, csr);
  k_agg1<<<NBK1 * 8, 256, 0, stream>>>(xlh, xrh, hb, offs, csr, att1, b1);
  k_gemm2m<<<(NN + 127) / 128, 256, 0, stream>>>(hb, wt2, h2lh, h2r);
  k_agg2<<<NN / 4, 256, 0, stream>>>(h2lh, h2r, offs, csr, att2, b2, out);
}